// Round 7
// baseline (1181.305 us; speedup 1.0000x reference)
//
#include <hip/hip_runtime.h>
#include <hip/hip_bf16.h>
#include <math.h>

// PointNet++ SA: FPS -> ball query -> gather -> 3x(1x1conv+BN+ReLU) -> maxpool(K)
// R6: FPS v7 — LDS-pipe diet: winner writes slot (key u64 + float4 coords);
//     combine = 1 gathered b64 + 1 gathered b128 per wave + in-register DPP
//     lexicographic max over 8 slots. Downstream identical to R6 (MFMA chains).

static constexpr int BATCH  = 16;
static constexpr int NPTS   = 4096;
static constexpr int NPOINT = 1024;
static constexpr int NSAMP  = 32;
static constexpr int CIN    = 64;
static constexpr int ROWS   = BATCH * NPOINT * NSAMP;  // 524288
static constexpr int NBLK   = ROWS / 64;               // 8192

typedef unsigned long long u64;
typedef float f32x4 __attribute__((ext_vector_type(4)));
typedef short short8v __attribute__((ext_vector_type(8)));

__device__ __forceinline__ float sqdist(float x, float y, float z,
                                        float cx, float cy, float cz) {
    // exact IEEE order: (dx*dx + dy*dy) + dz*dz, no fma contraction (matches reference f32)
    float dx = x - cx, dy = y - cy, dz = z - cz;
    return __fadd_rn(__fadd_rn(__fmul_rn(dx, dx), __fmul_rn(dy, dy)), __fmul_rn(dz, dz));
}

#if __has_builtin(__builtin_amdgcn_update_dpp) && __has_builtin(__builtin_amdgcn_readlane)
#define HAVE_DPP 1
#define DPP_FMAX(x, ctrl)                                                             \
    do {                                                                              \
        int _o = __builtin_amdgcn_update_dpp(__float_as_int(x), __float_as_int(x),    \
                                             (ctrl), 0xf, 0xf, false);                \
        (x) = fmaxf((x), __int_as_float(_o));                                         \
    } while (0)
#define WAVE_RED_F(x) do { DPP_FMAX(x,0x111); DPP_FMAX(x,0x112); DPP_FMAX(x,0x114); \
                           DPP_FMAX(x,0x118); DPP_FMAX(x,0x142); DPP_FMAX(x,0x143); } while (0)
__device__ __forceinline__ float bcast63(float v) {
    return __int_as_float(__builtin_amdgcn_readlane(__float_as_int(v), 63));
}
#define RLANE_U(v, l) ((unsigned)__builtin_amdgcn_readlane((int)(v), (l)))
#define RLANE_F(v, l) __int_as_float(__builtin_amdgcn_readlane(__float_as_int(v), (l)))
// one lexicographic-max pull step over (khi,klo,x,y,z) from lane (i-n) via DPP row_shr:n
#define RED8_STEP(ctrl)                                                               \
    do {                                                                              \
        unsigned _ohi = (unsigned)__builtin_amdgcn_update_dpp((int)khi, (int)khi, (ctrl), 0xf, 0xf, false); \
        unsigned _olo = (unsigned)__builtin_amdgcn_update_dpp((int)klo, (int)klo, (ctrl), 0xf, 0xf, false); \
        float _ox = __int_as_float(__builtin_amdgcn_update_dpp(__float_as_int(wx), __float_as_int(wx), (ctrl), 0xf, 0xf, false)); \
        float _oy = __int_as_float(__builtin_amdgcn_update_dpp(__float_as_int(wy), __float_as_int(wy), (ctrl), 0xf, 0xf, false)); \
        float _oz = __int_as_float(__builtin_amdgcn_update_dpp(__float_as_int(wz), __float_as_int(wz), (ctrl), 0xf, 0xf, false)); \
        bool _take = (_ohi > khi) || (_ohi == khi && _olo > klo);                     \
        khi = _take ? _ohi : khi; klo = _take ? _olo : klo;                           \
        wx = _take ? _ox : wx; wy = _take ? _oy : wy; wz = _take ? _oz : wz;          \
    } while (0)
#else
#define HAVE_DPP 0
#define WAVE_RED_F(x) do { for (int _m = 1; _m < 64; _m <<= 1) (x) = fmaxf((x), __shfl_xor((x), _m)); } while (0)
__device__ __forceinline__ float bcast63(float v) { return __shfl(v, 63); }
#define RLANE_U(v, l) ((unsigned)__shfl((int)(v), (l)))
#define RLANE_F(v, l) __shfl((v), (l))
#define RED8_STEP_SHFL(n)                                                             \
    do {                                                                              \
        unsigned _ohi = (unsigned)__shfl_up((int)khi, (n));                           \
        unsigned _olo = (unsigned)__shfl_up((int)klo, (n));                           \
        float _ox = __shfl_up(wx, (n)); float _oy = __shfl_up(wy, (n));               \
        float _oz = __shfl_up(wz, (n));                                               \
        bool _take = ((lane & 63) >= (n)) &&                                          \
                     ((_ohi > khi) || (_ohi == khi && _olo > klo));                   \
        khi = _take ? _ohi : khi; klo = _take ? _olo : klo;                           \
        wx = _take ? _ox : wx; wy = _take ? _oy : wy; wz = _take ? _oz : wz;          \
    } while (0)
#endif

__device__ __forceinline__ unsigned short f2bf(float v) {
    union { __hip_bfloat16 b; unsigned short u; } c;
    c.b = __float2bfloat16(v);
    return c.u;
}

// byte offset of (row, byte_in_row) in a [rows][128B] LDS tile, XOR-swizzled
__device__ __forceinline__ int swz(int row, int bir) {
    return (row << 7) | (bir ^ ((row & 7) << 4));
}

// Load a 16x16x32 bf16 MFMA operand fragment (same k-convention for A and B).
__device__ __forceinline__ short8v load_frag(const char* b, int row, int k0) {
    union { uint2 v; short s[4]; } lo, hi;
    lo.v = *(const uint2*)(b + swz(row, 2 * k0));
    hi.v = *(const uint2*)(b + swz(row, 2 * k0 + 32));
    short8v f;
    f[0] = lo.s[0]; f[1] = lo.s[1]; f[2] = lo.s[2]; f[3] = lo.s[3];
    f[4] = hi.s[0]; f[5] = hi.s[1]; f[6] = hi.s[2]; f[7] = hi.s[3];
    return f;
}

// ---------------- fused: blocks [0,16) = FPS per batch; [16,528) = P GEMM tiles ----
__global__ __launch_bounds__(512) void pre_kernel(
    const float* __restrict__ xyz, const float* __restrict__ points,
    const float* __restrict__ w0, const float* __restrict__ b0,
    float* __restrict__ P, float* __restrict__ new_xyz) {
    __shared__ __align__(16) char s_raw[53632];
    const int tid = threadIdx.x;

    if (blockIdx.x < 16) {
        // ================= FPS role (512 thr, 8 waves) =================
        float2* sxy    = (float2*)s_raw;             // 32768 B
        float*  szv    = (float*)(s_raw + 32768);    // 16384 B
        int*    s_cent = (int*)(s_raw + 49152);      //  4096 B
        u64*    s_key  = (u64*)(s_raw + 53248);      //  128 B  [2][8]
        float4* s_xyz  = (float4*)(s_raw + 53376);   //  256 B  [2][8]

        const int b = blockIdx.x;
        const float* xb = xyz + (size_t)b * NPTS * 3;
        for (int p = tid; p < NPTS; p += 512) {
            sxy[p] = make_float2(xb[p * 3 + 0], xb[p * 3 + 1]);
            szv[p] = xb[p * 3 + 2];
        }
        __syncthreads();
        float px[8], py[8], pz[8], dist[8];
#pragma unroll
        for (int j = 0; j < 8; ++j) {
            int p = tid + j * 512;
            float2 f = sxy[p];
            px[j] = f.x; py[j] = f.y; pz[j] = szv[p];
            dist[j] = 1e10f;
        }
        const int lane = tid & 63, wid = tid >> 6;
        int far = 0;
        float2 c0 = sxy[0];
        float cx = c0.x, cy = c0.y, cz = szv[0];
        for (int it = 0; it < NPOINT; ++it) {
            if (tid == 0) s_cent[it] = far;
            float bv = -1.0f;
            int   bi = 0;
            float bx = 0.f, by = 0.f, bz = 0.f;
#pragma unroll
            for (int j = 0; j < 8; ++j) {
                float d  = sqdist(px[j], py[j], pz[j], cx, cy, cz);
                float nd = fminf(dist[j], d);   // jnp.minimum
                dist[j]  = nd;
                bool gt = (nd > bv);            // j asc -> smallest idx on tie (intra-thread)
                bv = gt ? nd : bv;  bi = gt ? (tid + j * 512) : bi;
                bx = gt ? px[j] : bx; by = gt ? py[j] : by; bz = gt ? pz[j] : bz;
            }
            float red = bv;
            WAVE_RED_F(red);                    // lane63: wave max
            float gmax = bcast63(red);
            u64 mask = __ballot(bv == gmax);
            int win = (int)__builtin_ctzll(mask);   // lane-order tie-break
            const int buf = (it & 1);
            if (lane == win) {
                // key: distbits | (4095-bi)<<3 | wid   (bi unique across waves ->
                // wid bits never decide a tie incorrectly)
                s_key[buf * 8 + wid] =
                    ((u64)__float_as_uint(bv) << 32) |
                    ((unsigned)(4095 - bi) << 3) | (unsigned)wid;
                s_xyz[buf * 8 + wid] = make_float4(bx, by, bz, 0.f);
            }
            __syncthreads();
            // gathered read: lane l -> slot (l&7); one b64 + one b128 per wave
            const int sl = lane & 7;
            u64   k = s_key[buf * 8 + sl];
            float4 c = s_xyz[buf * 8 + sl];
            unsigned khi = (unsigned)(k >> 32), klo = (unsigned)k;
            float wx = c.x, wy = c.y, wz = c.z;
#if HAVE_DPP
            RED8_STEP(0x111);   // row_shr:1
            RED8_STEP(0x112);   // row_shr:2
            RED8_STEP(0x114);   // row_shr:4  -> lane 7 holds max over slots 0..7
#else
            RED8_STEP_SHFL(1); RED8_STEP_SHFL(2); RED8_STEP_SHFL(4);
#endif
            unsigned klo7 = RLANE_U(klo, 7);
            far = 4095 - (int)((klo7 >> 3) & 0xFFFu);
            cx = RLANE_F(wx, 7); cy = RLANE_F(wy, 7); cz = RLANE_F(wz, 7);
        }
        __syncthreads();
        for (int s = tid; s < NPOINT; s += 512) {
            int c = s_cent[s];
            float2 f = sxy[c];
            new_xyz[((size_t)b * NPOINT + s) * 3 + 0] = f.x;
            new_xyz[((size_t)b * NPOINT + s) * 3 + 1] = f.y;
            new_xyz[((size_t)b * NPOINT + s) * 3 + 2] = szv[c];
        }
    } else {
        // ================= P role: P[n] = W0*[xyz,points]+b0, 128-pt tile =========
        float (*xw)[68] = (float(*)[68])s_raw;             // 34816 B
        float (*wt)[68] = (float(*)[68])(s_raw + 34816);   // 17408 B
        const int blk = blockIdx.x - 16;
        const int pt0 = blk * 128;
        const int ty = tid >> 4, tx = tid & 15;

        for (int idx = tid; idx < 128 * 3; idx += 512) {
            int r = idx / 3, d = idx - r * 3;
            xw[r][d] = xyz[(size_t)(pt0 + r) * 3 + d];
        }
        for (int idx = tid; idx < 128 * 16; idx += 512) {
            int r = idx >> 4, c4 = idx & 15;
            float4 v = *(const float4*)(points + (size_t)(pt0 + r) * CIN + c4 * 4);
            xw[r][3 + c4 * 4 + 0] = v.x;
            xw[r][3 + c4 * 4 + 1] = v.y;
            xw[r][3 + c4 * 4 + 2] = v.z;
            xw[r][3 + c4 * 4 + 3] = v.w;
        }
        for (int idx = tid; idx < 64 * 67; idx += 512) {
            int o = idx / 67, c = idx - o * 67;
            wt[o][c] = w0[idx];
        }
        __syncthreads();

        float acc[4][4];
        {
            float bj[4];
#pragma unroll
            for (int j = 0; j < 4; ++j) bj[j] = b0[tx + 16 * j];
#pragma unroll
            for (int i = 0; i < 4; ++i)
#pragma unroll
                for (int j = 0; j < 4; ++j) acc[i][j] = bj[j];
        }
        for (int c4 = 0; c4 < 64; c4 += 4) {
            float4 xv[4], wv[4];
#pragma unroll
            for (int i = 0; i < 4; ++i) xv[i] = *(const float4*)&xw[ty + 32 * i][c4];
#pragma unroll
            for (int j = 0; j < 4; ++j) wv[j] = *(const float4*)&wt[tx + 16 * j][c4];
#pragma unroll
            for (int i = 0; i < 4; ++i)
#pragma unroll
                for (int j = 0; j < 4; ++j)
                    acc[i][j] += xv[i].x * wv[j].x + xv[i].y * wv[j].y +
                                 xv[i].z * wv[j].z + xv[i].w * wv[j].w;
        }
#pragma unroll
        for (int c = 64; c < 67; ++c) {
            float xv[4], wv[4];
#pragma unroll
            for (int i = 0; i < 4; ++i) xv[i] = xw[ty + 32 * i][c];
#pragma unroll
            for (int j = 0; j < 4; ++j) wv[j] = wt[tx + 16 * j][c];
#pragma unroll
            for (int i = 0; i < 4; ++i)
#pragma unroll
                for (int j = 0; j < 4; ++j) acc[i][j] += xv[i] * wv[j];
        }
#pragma unroll
        for (int i = 0; i < 4; ++i)
#pragma unroll
            for (int j = 0; j < 4; ++j)
                P[(size_t)(pt0 + ty + 32 * i) * 64 + tx + 16 * j] = acc[i][j];
    }
}

// ---------------- ball query (+ fused Q): one wave per (b,s) ----------------
__global__ __launch_bounds__(256) void ballq_kernel(const float* __restrict__ xyz,
                                                    const float* __restrict__ new_xyz,
                                                    const float* __restrict__ w0,
                                                    int* __restrict__ gi,
                                                    float* __restrict__ Q) {
    const int lane = threadIdx.x & 63;
    const int w    = threadIdx.x >> 6;
    const int pair = blockIdx.x * 4 + w;   // b*NPOINT + s
    const int b    = pair >> 10;
    const float R2 = (float)(0.4 * 0.4);
    const float* xb = xyz + (size_t)b * NPTS * 3;
    const float cx = new_xyz[pair * 3 + 0];
    const float cy = new_xyz[pair * 3 + 1];
    const float cz = new_xyz[pair * 3 + 2];
    int* g = gi + (size_t)pair * NSAMP;

    Q[(size_t)pair * 64 + lane] =
        w0[lane * 67 + 0] * cx + w0[lane * 67 + 1] * cy + w0[lane * 67 + 2] * cz;

    int found = 0, first = 0;
    bool have_first = false;
    for (int c0 = 0; c0 < NPTS; c0 += 64) {
        const int n = c0 + lane;
        float d = sqdist(xb[n * 3 + 0], xb[n * 3 + 1], xb[n * 3 + 2], cx, cy, cz);
        bool in = !(d > R2);
        unsigned long long m = __ballot(in);
        if (m) {
            if (!have_first) { first = c0 + (__ffsll(m) - 1); have_first = true; }
            if (in) {
                int slot = found + (int)__popcll(m & ((1ull << lane) - 1ull));
                if (slot < NSAMP) g[slot] = n;
            }
            found += (int)__popcll(m);
            if (found >= NSAMP) break;
        }
    }
    for (int slot = found + lane; slot < NSAMP; slot += 64) g[slot] = first;
}

// ---------------- stats of raw y0 = P[n] - Q[s]  (fp32, exact) ----------------
__global__ __launch_bounds__(256) void stats0_kernel(
    const float* __restrict__ P, const float* __restrict__ Q,
    const int* __restrict__ gi, float* __restrict__ partial) {
    __shared__ __align__(16) float xw[64][68];
    __shared__ int s_n[64];
    const int tid = threadIdx.x, blk = blockIdx.x;
    const int row0 = blk * 64;
    if (tid < 64) s_n[tid] = ((row0 + tid) >> 15) * NPTS + gi[row0 + tid];
    __syncthreads();
    for (int idx = tid; idx < 64 * 16; idx += 256) {
        int r = idx >> 4, c4 = idx & 15;
        float4 pv = *(const float4*)(P + ((size_t)s_n[r] << 6) + c4 * 4);
        float4 qv = *(const float4*)(Q + ((size_t)(blk * 2 + (r >> 5)) << 6) + c4 * 4);
        float4 y; y.x = pv.x - qv.x; y.y = pv.y - qv.y; y.z = pv.z - qv.z; y.w = pv.w - qv.w;
        *(float4*)&xw[r][c4 * 4] = y;
    }
    __syncthreads();
    if (tid < 64) {
        float s = 0.f, q = 0.f;
        for (int r = 0; r < 64; ++r) { float v = xw[r][tid]; s += v; q += v * v; }
        partial[(size_t)blk * 128 + tid]      = s;
        partial[(size_t)blk * 128 + 64 + tid] = q;
    }
}

// ============ MFMA chain kernels ============
__global__ __launch_bounds__(256) void chainM1_kernel(
    const float* __restrict__ P, const float* __restrict__ Q,
    const int* __restrict__ gi, const float* __restrict__ w1, const float* __restrict__ b1,
    const float* __restrict__ ss, float* __restrict__ partial) {
    __shared__ __align__(16) char h0b[64 * 128];    // bf16 [64][64] swizzled
    __shared__ __align__(16) char w1b[64 * 128];    // bf16 [64][64] swizzled
    __shared__ float sredS[4][64], sredQ[4][64];
    __shared__ int s_n[64];
    const int tid = threadIdx.x, blk = blockIdx.x;
    const int row0 = blk * 64;
    if (tid < 64) s_n[tid] = ((row0 + tid) >> 15) * NPTS + gi[row0 + tid];
    for (int idx = tid; idx < 1024; idx += 256) {
        float4 v = *(const float4*)(w1 + idx * 4);
        uint2 pk; pk.x = (unsigned)f2bf(v.x) | ((unsigned)f2bf(v.y) << 16);
        pk.y = (unsigned)f2bf(v.z) | ((unsigned)f2bf(v.w) << 16);
        *(uint2*)(w1b + swz(idx >> 4, 8 * (idx & 15))) = pk;
    }
    __syncthreads();
    for (int idx = tid; idx < 1024; idx += 256) {
        int r = idx >> 4, c0 = (idx & 15) * 4;
        float4 pv = *(const float4*)(P + ((size_t)s_n[r] << 6) + c0);
        float4 qv = *(const float4*)(Q + ((size_t)(blk * 2 + (r >> 5)) << 6) + c0);
        float4 sc = *(const float4*)(ss + c0);
        float4 sh = *(const float4*)(ss + 128 + c0);
        float y0 = fmaxf((pv.x - qv.x) * sc.x + sh.x, 0.f);
        float y1v = fmaxf((pv.y - qv.y) * sc.y + sh.y, 0.f);
        float y2v = fmaxf((pv.z - qv.z) * sc.z + sh.z, 0.f);
        float y3 = fmaxf((pv.w - qv.w) * sc.w + sh.w, 0.f);
        uint2 pk; pk.x = (unsigned)f2bf(y0) | ((unsigned)f2bf(y1v) << 16);
        pk.y = (unsigned)f2bf(y2v) | ((unsigned)f2bf(y3) << 16);
        *(uint2*)(h0b + swz(r, 8 * (idx & 15))) = pk;
    }
    __syncthreads();

    const int l = tid & 63, w = tid >> 6;
    const int mrow = 16 * w + (l & 15);
    const int klane = (l >> 4) * 4;
    short8v a0 = load_frag(h0b, mrow, klane);
    short8v a1 = load_frag(h0b, mrow, klane + 32);
#pragma unroll
    for (int nt = 0; nt < 4; ++nt) {
        float bias = b1[16 * nt + (l & 15)];
        f32x4 acc; acc[0] = bias; acc[1] = bias; acc[2] = bias; acc[3] = bias;
        short8v bA = load_frag(w1b, 16 * nt + (l & 15), klane);
        short8v bB = load_frag(w1b, 16 * nt + (l & 15), klane + 32);
        acc = __builtin_amdgcn_mfma_f32_16x16x32_bf16(a0, bA, acc, 0, 0, 0);
        acc = __builtin_amdgcn_mfma_f32_16x16x32_bf16(a1, bB, acc, 0, 0, 0);
        float s = acc[0] + acc[1] + acc[2] + acc[3];
        float q = acc[0] * acc[0] + acc[1] * acc[1] + acc[2] * acc[2] + acc[3] * acc[3];
        s += __shfl_xor(s, 16); s += __shfl_xor(s, 32);
        q += __shfl_xor(q, 16); q += __shfl_xor(q, 32);
        if (l < 16) { sredS[w][nt * 16 + l] = s; sredQ[w][nt * 16 + l] = q; }
    }
    __syncthreads();
    if (tid < 64) {
        float s = sredS[0][tid] + sredS[1][tid] + sredS[2][tid] + sredS[3][tid];
        float q = sredQ[0][tid] + sredQ[1][tid] + sredQ[2][tid] + sredQ[3][tid];
        partial[(size_t)blk * 128 + tid]      = s;
        partial[(size_t)blk * 128 + 64 + tid] = q;
    }
}

__global__ __launch_bounds__(256) void chainM2_kernel(
    const float* __restrict__ P, const float* __restrict__ Q,
    const int* __restrict__ gi,
    const float* __restrict__ w1, const float* __restrict__ b1,
    const float* __restrict__ w2, const float* __restrict__ b2,
    const float* __restrict__ ss, float* __restrict__ partial,
    float* __restrict__ maxy) {
    __shared__ __align__(16) char h0b[64 * 128];
    __shared__ __align__(16) char w1b[64 * 128];
    __shared__ __align__(16) char h1b[64 * 128];
    __shared__ __align__(16) char w2b[128 * 128];
    __shared__ float sredS[4][128], sredQ[4][128], sredM[4][128];
    __shared__ int s_n[64];
    const int tid = threadIdx.x, blk = blockIdx.x;
    const int row0 = blk * 64;
    if (tid < 64) s_n[tid] = ((row0 + tid) >> 15) * NPTS + gi[row0 + tid];
    for (int idx = tid; idx < 1024; idx += 256) {
        float4 v = *(const float4*)(w1 + idx * 4);
        uint2 pk; pk.x = (unsigned)f2bf(v.x) | ((unsigned)f2bf(v.y) << 16);
        pk.y = (unsigned)f2bf(v.z) | ((unsigned)f2bf(v.w) << 16);
        *(uint2*)(w1b + swz(idx >> 4, 8 * (idx & 15))) = pk;
    }
    for (int idx = tid; idx < 2048; idx += 256) {
        float4 v = *(const float4*)(w2 + idx * 4);
        uint2 pk; pk.x = (unsigned)f2bf(v.x) | ((unsigned)f2bf(v.y) << 16);
        pk.y = (unsigned)f2bf(v.z) | ((unsigned)f2bf(v.w) << 16);
        *(uint2*)(w2b + swz(idx >> 4, 8 * (idx & 15))) = pk;
    }
    __syncthreads();
    for (int idx = tid; idx < 1024; idx += 256) {
        int r = idx >> 4, c0 = (idx & 15) * 4;
        float4 pv = *(const float4*)(P + ((size_t)s_n[r] << 6) + c0);
        float4 qv = *(const float4*)(Q + ((size_t)(blk * 2 + (r >> 5)) << 6) + c0);
        float4 sc = *(const float4*)(ss + c0);
        float4 sh = *(const float4*)(ss + 128 + c0);
        float y0 = fmaxf((pv.x - qv.x) * sc.x + sh.x, 0.f);
        float y1v = fmaxf((pv.y - qv.y) * sc.y + sh.y, 0.f);
        float y2v = fmaxf((pv.z - qv.z) * sc.z + sh.z, 0.f);
        float y3 = fmaxf((pv.w - qv.w) * sc.w + sh.w, 0.f);
        uint2 pk; pk.x = (unsigned)f2bf(y0) | ((unsigned)f2bf(y1v) << 16);
        pk.y = (unsigned)f2bf(y2v) | ((unsigned)f2bf(y3) << 16);
        *(uint2*)(h0b + swz(r, 8 * (idx & 15))) = pk;
    }
    __syncthreads();

    const int l = tid & 63, w = tid >> 6;
    const int mrow = 16 * w + (l & 15);
    const int klane = (l >> 4) * 4;
    {
        short8v a0 = load_frag(h0b, mrow, klane);
        short8v a1 = load_frag(h0b, mrow, klane + 32);
#pragma unroll
        for (int nt = 0; nt < 4; ++nt) {
            float bias = b1[16 * nt + (l & 15)];
            f32x4 acc; acc[0] = bias; acc[1] = bias; acc[2] = bias; acc[3] = bias;
            short8v bA = load_frag(w1b, 16 * nt + (l & 15), klane);
            short8v bB = load_frag(w1b, 16 * nt + (l & 15), klane + 32);
            acc = __builtin_amdgcn_mfma_f32_16x16x32_bf16(a0, bA, acc, 0, 0, 0);
            acc = __builtin_amdgcn_mfma_f32_16x16x32_bf16(a1, bB, acc, 0, 0, 0);
#pragma unroll
            for (int p = 0; p < 4; ++p) {
                int row = 16 * w + (l >> 4) * 4 + p;
                int col = 16 * nt + (l & 15);
                float v = fmaxf(acc[p] * ss[256 + col] + ss[384 + col], 0.f);
                *(unsigned short*)(h1b + swz(row, 2 * col)) = f2bf(v);
            }
        }
    }
    __syncthreads();
    {
        short8v a0 = load_frag(h1b, mrow, klane);
        short8v a1 = load_frag(h1b, mrow, klane + 32);
#pragma unroll
        for (int nt = 0; nt < 8; ++nt) {
            float bias = b2[16 * nt + (l & 15)];
            f32x4 acc; acc[0] = bias; acc[1] = bias; acc[2] = bias; acc[3] = bias;
            short8v bA = load_frag(w2b, 16 * nt + (l & 15), klane);
            short8v bB = load_frag(w2b, 16 * nt + (l & 15), klane + 32);
            acc = __builtin_amdgcn_mfma_f32_16x16x32_bf16(a0, bA, acc, 0, 0, 0);
            acc = __builtin_amdgcn_mfma_f32_16x16x32_bf16(a1, bB, acc, 0, 0, 0);
            float s = acc[0] + acc[1] + acc[2] + acc[3];
            float q = acc[0] * acc[0] + acc[1] * acc[1] + acc[2] * acc[2] + acc[3] * acc[3];
            float m = fmaxf(fmaxf(acc[0], acc[1]), fmaxf(acc[2], acc[3]));
            s += __shfl_xor(s, 16); s += __shfl_xor(s, 32);
            q += __shfl_xor(q, 16); q += __shfl_xor(q, 32);
            m = fmaxf(m, __shfl_xor(m, 16)); m = fmaxf(m, __shfl_xor(m, 32));
            if (l < 16) {
                sredS[w][nt * 16 + l] = s;
                sredQ[w][nt * 16 + l] = q;
                sredM[w][nt * 16 + l] = m;
            }
        }
    }
    __syncthreads();
    if (tid < 128) {
        float s = sredS[0][tid] + sredS[1][tid] + sredS[2][tid] + sredS[3][tid];
        float q = sredQ[0][tid] + sredQ[1][tid] + sredQ[2][tid] + sredQ[3][tid];
        partial[(size_t)blk * 256 + tid]       = s;
        partial[(size_t)blk * 256 + 128 + tid] = q;
        const int bs0 = blk * 2;
        maxy[(size_t)bs0 * 128 + tid]       = fmaxf(sredM[0][tid], sredM[1][tid]);
        maxy[(size_t)(bs0 + 1) * 128 + tid] = fmaxf(sredM[2][tid], sredM[3][tid]);
    }
}

// ---------------- reduce stats -> scale/shift ----------------
__global__ __launch_bounds__(256) void reduce_stats_kernel(
    const float* __restrict__ partial, int Cd, float inv_count,
    const float* __restrict__ g, const float* __restrict__ be,
    float* __restrict__ ss_layer) {
    const int c   = blockIdx.x;
    const int tid = threadIdx.x;
    float s = 0.f, q = 0.f;
    for (int blk = tid; blk < NBLK; blk += 256) {
        s += partial[(size_t)blk * 2 * Cd + c];
        q += partial[(size_t)blk * 2 * Cd + Cd + c];
    }
#pragma unroll
    for (int m = 1; m < 64; m <<= 1) { s += __shfl_xor(s, m); q += __shfl_xor(q, m); }
    __shared__ float ls[4], lq[4];
    const int wid = tid >> 6;
    if ((tid & 63) == 0) { ls[wid] = s; lq[wid] = q; }
    __syncthreads();
    if (tid == 0) {
        s = ls[0] + ls[1] + ls[2] + ls[3];
        q = lq[0] + lq[1] + lq[2] + lq[3];
        float mean = s * inv_count;
        float var  = q * inv_count - mean * mean;
        float sc   = g[c] / sqrtf(var + 1e-5f);
        ss_layer[c]       = sc;
        ss_layer[128 + c] = be[c] - mean * sc;
    }
}

// ---------------- final: BN2 + ReLU applied to max-pooled y2 ----------------
__global__ __launch_bounds__(256) void final_kernel(const float* __restrict__ maxy,
                                                    const float* __restrict__ ss2,
                                                    float* __restrict__ outp) {
    int idx = blockIdx.x * 256 + threadIdx.x;
    int c = idx & 127;
    float v = maxy[idx] * ss2[c] + ss2[128 + c];
    outp[idx] = fmaxf(v, 0.f);
}

extern "C" void kernel_launch(void* const* d_in, const int* in_sizes, int n_in,
                              void* d_out, int out_size, void* d_ws, size_t ws_size,
                              hipStream_t stream) {
    const float* xyz    = (const float*)d_in[0];
    const float* points = (const float*)d_in[1];
    const float* w0 = (const float*)d_in[2];  const float* b0  = (const float*)d_in[3];
    const float* g0 = (const float*)d_in[4];  const float* be0 = (const float*)d_in[5];
    const float* w1 = (const float*)d_in[6];  const float* b1  = (const float*)d_in[7];
    const float* g1 = (const float*)d_in[8];  const float* be1 = (const float*)d_in[9];
    const float* w2 = (const float*)d_in[10]; const float* b2  = (const float*)d_in[11];
    const float* g2 = (const float*)d_in[12]; const float* be2 = (const float*)d_in[13];

    float* out      = (float*)d_out;
    float* new_xyz  = out;                                 // [B, S, 3]
    float* out_pts  = out + (size_t)BATCH * NPOINT * 3;    // [B, S, 128]

    char* p = (char*)d_ws;
    int* gi = (int*)p;          p += (((size_t)ROWS * 4) + 255) & ~(size_t)255;
    float* partial = (float*)p; p += (((size_t)NBLK * 256 * 4) + 255) & ~(size_t)255;
    float* ss = (float*)p;      p += ((size_t)(3 * 256 * 4) + 255) & ~(size_t)255;
    float* maxy = (float*)p;    p += (((size_t)BATCH * NPOINT * 128 * 4) + 255) & ~(size_t)255;
    float* P = (float*)p;       p += (((size_t)BATCH * NPTS * 64 * 4) + 255) & ~(size_t)255;
    float* Q = (float*)p;       // [B*NPOINT][64]

    const float inv_count = 1.0f / (float)ROWS;

    pre_kernel<<<16 + 512, 512, 0, stream>>>(xyz, points, w0, b0, P, new_xyz);
    ballq_kernel<<<(BATCH * NPOINT) / 4, 256, 0, stream>>>(xyz, new_xyz, w0, gi, Q);

    stats0_kernel<<<NBLK, 256, 0, stream>>>(P, Q, gi, partial);
    reduce_stats_kernel<<<64, 256, 0, stream>>>(partial, 64, inv_count, g0, be0, ss + 0);

    chainM1_kernel<<<NBLK, 256, 0, stream>>>(P, Q, gi, w1, b1, ss, partial);
    reduce_stats_kernel<<<64, 256, 0, stream>>>(partial, 64, inv_count, g1, be1, ss + 256);

    chainM2_kernel<<<NBLK, 256, 0, stream>>>(P, Q, gi, w1, b1, w2, b2, ss, partial, maxy);
    reduce_stats_kernel<<<128, 256, 0, stream>>>(partial, 128, inv_count, g2, be2, ss + 512);

    final_kernel<<<(BATCH * NPOINT * 128) / 256, 256, 0, stream>>>(maxy, ss + 512, out_pts);
}

// Round 8
// 908.035 us; speedup vs baseline: 1.3009x; 1.3009x over previous
//
#include <hip/hip_runtime.h>
#include <hip/hip_bf16.h>
#include <math.h>

// PointNet++ SA: FPS -> ball query -> gather -> 3x(1x1conv+BN+ReLU) -> maxpool(K)
// R7: FPS reverted to measured-best R3 structure (661us): DPP fmax + ballot/ctz +
//     shfl widx + lane0 slot write + barrier + broadcast scalar-tree combine.
//     Keeps: P fused under FPS launch, ballq+Q fusion, bf16-MFMA chain kernels.

static constexpr int BATCH  = 16;
static constexpr int NPTS   = 4096;
static constexpr int NPOINT = 1024;
static constexpr int NSAMP  = 32;
static constexpr int CIN    = 64;
static constexpr int ROWS   = BATCH * NPOINT * NSAMP;  // 524288
static constexpr int NBLK   = ROWS / 64;               // 8192

typedef unsigned long long u64;
typedef float f32x4 __attribute__((ext_vector_type(4)));
typedef short short8v __attribute__((ext_vector_type(8)));

__device__ __forceinline__ float sqdist(float x, float y, float z,
                                        float cx, float cy, float cz) {
    // exact IEEE order: (dx*dx + dy*dy) + dz*dz, no fma contraction (matches reference f32)
    float dx = x - cx, dy = y - cy, dz = z - cz;
    return __fadd_rn(__fadd_rn(__fmul_rn(dx, dx), __fmul_rn(dy, dy)), __fmul_rn(dz, dz));
}

#if __has_builtin(__builtin_amdgcn_update_dpp) && __has_builtin(__builtin_amdgcn_readlane)
#define DPP_FMAX(x, ctrl)                                                             \
    do {                                                                              \
        int _o = __builtin_amdgcn_update_dpp(__float_as_int(x), __float_as_int(x),    \
                                             (ctrl), 0xf, 0xf, false);                \
        (x) = fmaxf((x), __int_as_float(_o));                                         \
    } while (0)
#define WAVE_RED_F(x) do { DPP_FMAX(x,0x111); DPP_FMAX(x,0x112); DPP_FMAX(x,0x114); \
                           DPP_FMAX(x,0x118); DPP_FMAX(x,0x142); DPP_FMAX(x,0x143); } while (0)
__device__ __forceinline__ float bcast63(float v) {
    return __int_as_float(__builtin_amdgcn_readlane(__float_as_int(v), 63));
}
#else
#define WAVE_RED_F(x) do { for (int _m = 1; _m < 64; _m <<= 1) (x) = fmaxf((x), __shfl_xor((x), _m)); } while (0)
__device__ __forceinline__ float bcast63(float v) { return __shfl(v, 63); }
#endif

__device__ __forceinline__ unsigned short f2bf(float v) {
    union { __hip_bfloat16 b; unsigned short u; } c;
    c.b = __float2bfloat16(v);
    return c.u;
}

// byte offset of (row, byte_in_row) in a [rows][128B] LDS tile, XOR-swizzled
__device__ __forceinline__ int swz(int row, int bir) {
    return (row << 7) | (bir ^ ((row & 7) << 4));
}

// Load a 16x16x32 bf16 MFMA operand fragment (same k-convention for A and B).
__device__ __forceinline__ short8v load_frag(const char* b, int row, int k0) {
    union { uint2 v; short s[4]; } lo, hi;
    lo.v = *(const uint2*)(b + swz(row, 2 * k0));
    hi.v = *(const uint2*)(b + swz(row, 2 * k0 + 32));
    short8v f;
    f[0] = lo.s[0]; f[1] = lo.s[1]; f[2] = lo.s[2]; f[3] = lo.s[3];
    f[4] = hi.s[0]; f[5] = hi.s[1]; f[6] = hi.s[2]; f[7] = hi.s[3];
    return f;
}

// ---------------- fused: blocks [0,16) = FPS per batch; [16,528) = P GEMM tiles ----
__global__ __launch_bounds__(512) void pre_kernel(
    const float* __restrict__ xyz, const float* __restrict__ points,
    const float* __restrict__ w0, const float* __restrict__ b0,
    float* __restrict__ P, float* __restrict__ new_xyz) {
    __shared__ __align__(16) char s_raw[53376];
    const int tid = threadIdx.x;

    if (blockIdx.x < 16) {
        // ================= FPS role (R3 structure, measured 661us) =================
        float2* sxy    = (float2*)s_raw;             // 32768 B
        float*  szv    = (float*)(s_raw + 32768);    // 16384 B
        int*    s_cent = (int*)(s_raw + 49152);      //  4096 B
        u64*    s_red  = (u64*)(s_raw + 53248);      //  128 B  [2][8]

        const int b = blockIdx.x;
        const float* xb = xyz + (size_t)b * NPTS * 3;
        for (int p = tid; p < NPTS; p += 512) {
            sxy[p] = make_float2(xb[p * 3 + 0], xb[p * 3 + 1]);
            szv[p] = xb[p * 3 + 2];
        }
        __syncthreads();
        float px[8], py[8], pz[8], dist[8];
#pragma unroll
        for (int j = 0; j < 8; ++j) {
            int p = tid + j * 512;
            float2 f = sxy[p];
            px[j] = f.x; py[j] = f.y; pz[j] = szv[p];
            dist[j] = 1e10f;
        }
        const int lane = tid & 63, wid = tid >> 6;
        int far = 0;
        for (int it = 0; it < NPOINT; ++it) {
            if (tid == 0) s_cent[it] = far;
            const float2 cxy = sxy[far];
            const float  cz  = szv[far];
            float bv = -1.0f;
            int   bi = 0;
#pragma unroll
            for (int j = 0; j < 8; ++j) {
                float d  = sqdist(px[j], py[j], pz[j], cxy.x, cxy.y, cz);
                float nd = fminf(dist[j], d);   // jnp.minimum
                dist[j]  = nd;
                if (nd > bv) { bv = nd; bi = tid + j * 512; }  // j asc -> smallest idx on tie
            }
            float gmax = bv;
            WAVE_RED_F(gmax);                   // lane63: wave max value
            gmax = bcast63(gmax);
            u64 mask = __ballot(bv == gmax);
            int widx = __shfl(bi, (int)__builtin_ctzll(mask));
            if (lane == 0)
                s_red[(it & 1) * 8 + wid] =
                    ((u64)__float_as_uint(gmax) << 32) | (unsigned)(4095 - widx);
            __syncthreads();
            const u64* sr = &s_red[(it & 1) * 8];
            u64 w = sr[0];
#pragma unroll
            for (int k = 1; k < 8; ++k) { u64 o = sr[k]; w = (o > w) ? o : w; }
            far = 4095 - (int)(w & 0xffffffffu);
        }
        __syncthreads();
        for (int s = tid; s < NPOINT; s += 512) {
            int c = s_cent[s];
            float2 f = sxy[c];
            new_xyz[((size_t)b * NPOINT + s) * 3 + 0] = f.x;
            new_xyz[((size_t)b * NPOINT + s) * 3 + 1] = f.y;
            new_xyz[((size_t)b * NPOINT + s) * 3 + 2] = szv[c];
        }
    } else {
        // ================= P role: P[n] = W0*[xyz,points]+b0, 128-pt tile =========
        float (*xw)[68] = (float(*)[68])s_raw;             // 34816 B
        float (*wt)[68] = (float(*)[68])(s_raw + 34816);   // 17408 B
        const int blk = blockIdx.x - 16;
        const int pt0 = blk * 128;
        const int ty = tid >> 4, tx = tid & 15;

        for (int idx = tid; idx < 128 * 3; idx += 512) {
            int r = idx / 3, d = idx - r * 3;
            xw[r][d] = xyz[(size_t)(pt0 + r) * 3 + d];
        }
        for (int idx = tid; idx < 128 * 16; idx += 512) {
            int r = idx >> 4, c4 = idx & 15;
            float4 v = *(const float4*)(points + (size_t)(pt0 + r) * CIN + c4 * 4);
            xw[r][3 + c4 * 4 + 0] = v.x;
            xw[r][3 + c4 * 4 + 1] = v.y;
            xw[r][3 + c4 * 4 + 2] = v.z;
            xw[r][3 + c4 * 4 + 3] = v.w;
        }
        for (int idx = tid; idx < 64 * 67; idx += 512) {
            int o = idx / 67, c = idx - o * 67;
            wt[o][c] = w0[idx];
        }
        __syncthreads();

        float acc[4][4];
        {
            float bj[4];
#pragma unroll
            for (int j = 0; j < 4; ++j) bj[j] = b0[tx + 16 * j];
#pragma unroll
            for (int i = 0; i < 4; ++i)
#pragma unroll
                for (int j = 0; j < 4; ++j) acc[i][j] = bj[j];
        }
        for (int c4 = 0; c4 < 64; c4 += 4) {
            float4 xv[4], wv[4];
#pragma unroll
            for (int i = 0; i < 4; ++i) xv[i] = *(const float4*)&xw[ty + 32 * i][c4];
#pragma unroll
            for (int j = 0; j < 4; ++j) wv[j] = *(const float4*)&wt[tx + 16 * j][c4];
#pragma unroll
            for (int i = 0; i < 4; ++i)
#pragma unroll
                for (int j = 0; j < 4; ++j)
                    acc[i][j] += xv[i].x * wv[j].x + xv[i].y * wv[j].y +
                                 xv[i].z * wv[j].z + xv[i].w * wv[j].w;
        }
#pragma unroll
        for (int c = 64; c < 67; ++c) {
            float xv[4], wv[4];
#pragma unroll
            for (int i = 0; i < 4; ++i) xv[i] = xw[ty + 32 * i][c];
#pragma unroll
            for (int j = 0; j < 4; ++j) wv[j] = wt[tx + 16 * j][c];
#pragma unroll
            for (int i = 0; i < 4; ++i)
#pragma unroll
                for (int j = 0; j < 4; ++j) acc[i][j] += xv[i] * wv[j];
        }
#pragma unroll
        for (int i = 0; i < 4; ++i)
#pragma unroll
            for (int j = 0; j < 4; ++j)
                P[(size_t)(pt0 + ty + 32 * i) * 64 + tx + 16 * j] = acc[i][j];
    }
}

// ---------------- ball query (+ fused Q): one wave per (b,s) ----------------
__global__ __launch_bounds__(256) void ballq_kernel(const float* __restrict__ xyz,
                                                    const float* __restrict__ new_xyz,
                                                    const float* __restrict__ w0,
                                                    int* __restrict__ gi,
                                                    float* __restrict__ Q) {
    const int lane = threadIdx.x & 63;
    const int w    = threadIdx.x >> 6;
    const int pair = blockIdx.x * 4 + w;   // b*NPOINT + s
    const int b    = pair >> 10;
    const float R2 = (float)(0.4 * 0.4);
    const float* xb = xyz + (size_t)b * NPTS * 3;
    const float cx = new_xyz[pair * 3 + 0];
    const float cy = new_xyz[pair * 3 + 1];
    const float cz = new_xyz[pair * 3 + 2];
    int* g = gi + (size_t)pair * NSAMP;

    Q[(size_t)pair * 64 + lane] =
        w0[lane * 67 + 0] * cx + w0[lane * 67 + 1] * cy + w0[lane * 67 + 2] * cz;

    int found = 0, first = 0;
    bool have_first = false;
    for (int c0 = 0; c0 < NPTS; c0 += 64) {
        const int n = c0 + lane;
        float d = sqdist(xb[n * 3 + 0], xb[n * 3 + 1], xb[n * 3 + 2], cx, cy, cz);
        bool in = !(d > R2);
        unsigned long long m = __ballot(in);
        if (m) {
            if (!have_first) { first = c0 + (__ffsll(m) - 1); have_first = true; }
            if (in) {
                int slot = found + (int)__popcll(m & ((1ull << lane) - 1ull));
                if (slot < NSAMP) g[slot] = n;
            }
            found += (int)__popcll(m);
            if (found >= NSAMP) break;
        }
    }
    for (int slot = found + lane; slot < NSAMP; slot += 64) g[slot] = first;
}

// ---------------- stats of raw y0 = P[n] - Q[s]  (fp32, exact) ----------------
__global__ __launch_bounds__(256) void stats0_kernel(
    const float* __restrict__ P, const float* __restrict__ Q,
    const int* __restrict__ gi, float* __restrict__ partial) {
    __shared__ __align__(16) float xw[64][68];
    __shared__ int s_n[64];
    const int tid = threadIdx.x, blk = blockIdx.x;
    const int row0 = blk * 64;
    if (tid < 64) s_n[tid] = ((row0 + tid) >> 15) * NPTS + gi[row0 + tid];
    __syncthreads();
    for (int idx = tid; idx < 64 * 16; idx += 256) {
        int r = idx >> 4, c4 = idx & 15;
        float4 pv = *(const float4*)(P + ((size_t)s_n[r] << 6) + c4 * 4);
        float4 qv = *(const float4*)(Q + ((size_t)(blk * 2 + (r >> 5)) << 6) + c4 * 4);
        float4 y; y.x = pv.x - qv.x; y.y = pv.y - qv.y; y.z = pv.z - qv.z; y.w = pv.w - qv.w;
        *(float4*)&xw[r][c4 * 4] = y;
    }
    __syncthreads();
    if (tid < 64) {
        float s = 0.f, q = 0.f;
        for (int r = 0; r < 64; ++r) { float v = xw[r][tid]; s += v; q += v * v; }
        partial[(size_t)blk * 128 + tid]      = s;
        partial[(size_t)blk * 128 + 64 + tid] = q;
    }
}

// ============ MFMA chain kernels ============
__global__ __launch_bounds__(256) void chainM1_kernel(
    const float* __restrict__ P, const float* __restrict__ Q,
    const int* __restrict__ gi, const float* __restrict__ w1, const float* __restrict__ b1,
    const float* __restrict__ ss, float* __restrict__ partial) {
    __shared__ __align__(16) char h0b[64 * 128];    // bf16 [64][64] swizzled
    __shared__ __align__(16) char w1b[64 * 128];    // bf16 [64][64] swizzled
    __shared__ float sredS[4][64], sredQ[4][64];
    __shared__ int s_n[64];
    const int tid = threadIdx.x, blk = blockIdx.x;
    const int row0 = blk * 64;
    if (tid < 64) s_n[tid] = ((row0 + tid) >> 15) * NPTS + gi[row0 + tid];
    for (int idx = tid; idx < 1024; idx += 256) {
        float4 v = *(const float4*)(w1 + idx * 4);
        uint2 pk; pk.x = (unsigned)f2bf(v.x) | ((unsigned)f2bf(v.y) << 16);
        pk.y = (unsigned)f2bf(v.z) | ((unsigned)f2bf(v.w) << 16);
        *(uint2*)(w1b + swz(idx >> 4, 8 * (idx & 15))) = pk;
    }
    __syncthreads();
    for (int idx = tid; idx < 1024; idx += 256) {
        int r = idx >> 4, c0 = (idx & 15) * 4;
        float4 pv = *(const float4*)(P + ((size_t)s_n[r] << 6) + c0);
        float4 qv = *(const float4*)(Q + ((size_t)(blk * 2 + (r >> 5)) << 6) + c0);
        float4 sc = *(const float4*)(ss + c0);
        float4 sh = *(const float4*)(ss + 128 + c0);
        float y0 = fmaxf((pv.x - qv.x) * sc.x + sh.x, 0.f);
        float y1v = fmaxf((pv.y - qv.y) * sc.y + sh.y, 0.f);
        float y2v = fmaxf((pv.z - qv.z) * sc.z + sh.z, 0.f);
        float y3 = fmaxf((pv.w - qv.w) * sc.w + sh.w, 0.f);
        uint2 pk; pk.x = (unsigned)f2bf(y0) | ((unsigned)f2bf(y1v) << 16);
        pk.y = (unsigned)f2bf(y2v) | ((unsigned)f2bf(y3) << 16);
        *(uint2*)(h0b + swz(r, 8 * (idx & 15))) = pk;
    }
    __syncthreads();

    const int l = tid & 63, w = tid >> 6;
    const int mrow = 16 * w + (l & 15);
    const int klane = (l >> 4) * 4;
    short8v a0 = load_frag(h0b, mrow, klane);
    short8v a1 = load_frag(h0b, mrow, klane + 32);
#pragma unroll
    for (int nt = 0; nt < 4; ++nt) {
        float bias = b1[16 * nt + (l & 15)];
        f32x4 acc; acc[0] = bias; acc[1] = bias; acc[2] = bias; acc[3] = bias;
        short8v bA = load_frag(w1b, 16 * nt + (l & 15), klane);
        short8v bB = load_frag(w1b, 16 * nt + (l & 15), klane + 32);
        acc = __builtin_amdgcn_mfma_f32_16x16x32_bf16(a0, bA, acc, 0, 0, 0);
        acc = __builtin_amdgcn_mfma_f32_16x16x32_bf16(a1, bB, acc, 0, 0, 0);
        float s = acc[0] + acc[1] + acc[2] + acc[3];
        float q = acc[0] * acc[0] + acc[1] * acc[1] + acc[2] * acc[2] + acc[3] * acc[3];
        s += __shfl_xor(s, 16); s += __shfl_xor(s, 32);
        q += __shfl_xor(q, 16); q += __shfl_xor(q, 32);
        if (l < 16) { sredS[w][nt * 16 + l] = s; sredQ[w][nt * 16 + l] = q; }
    }
    __syncthreads();
    if (tid < 64) {
        float s = sredS[0][tid] + sredS[1][tid] + sredS[2][tid] + sredS[3][tid];
        float q = sredQ[0][tid] + sredQ[1][tid] + sredQ[2][tid] + sredQ[3][tid];
        partial[(size_t)blk * 128 + tid]      = s;
        partial[(size_t)blk * 128 + 64 + tid] = q;
    }
}

__global__ __launch_bounds__(256) void chainM2_kernel(
    const float* __restrict__ P, const float* __restrict__ Q,
    const int* __restrict__ gi,
    const float* __restrict__ w1, const float* __restrict__ b1,
    const float* __restrict__ w2, const float* __restrict__ b2,
    const float* __restrict__ ss, float* __restrict__ partial,
    float* __restrict__ maxy) {
    __shared__ __align__(16) char h0b[64 * 128];
    __shared__ __align__(16) char w1b[64 * 128];
    __shared__ __align__(16) char h1b[64 * 128];
    __shared__ __align__(16) char w2b[128 * 128];
    __shared__ float sredS[4][128], sredQ[4][128], sredM[4][128];
    __shared__ int s_n[64];
    const int tid = threadIdx.x, blk = blockIdx.x;
    const int row0 = blk * 64;
    if (tid < 64) s_n[tid] = ((row0 + tid) >> 15) * NPTS + gi[row0 + tid];
    for (int idx = tid; idx < 1024; idx += 256) {
        float4 v = *(const float4*)(w1 + idx * 4);
        uint2 pk; pk.x = (unsigned)f2bf(v.x) | ((unsigned)f2bf(v.y) << 16);
        pk.y = (unsigned)f2bf(v.z) | ((unsigned)f2bf(v.w) << 16);
        *(uint2*)(w1b + swz(idx >> 4, 8 * (idx & 15))) = pk;
    }
    for (int idx = tid; idx < 2048; idx += 256) {
        float4 v = *(const float4*)(w2 + idx * 4);
        uint2 pk; pk.x = (unsigned)f2bf(v.x) | ((unsigned)f2bf(v.y) << 16);
        pk.y = (unsigned)f2bf(v.z) | ((unsigned)f2bf(v.w) << 16);
        *(uint2*)(w2b + swz(idx >> 4, 8 * (idx & 15))) = pk;
    }
    __syncthreads();
    for (int idx = tid; idx < 1024; idx += 256) {
        int r = idx >> 4, c0 = (idx & 15) * 4;
        float4 pv = *(const float4*)(P + ((size_t)s_n[r] << 6) + c0);
        float4 qv = *(const float4*)(Q + ((size_t)(blk * 2 + (r >> 5)) << 6) + c0);
        float4 sc = *(const float4*)(ss + c0);
        float4 sh = *(const float4*)(ss + 128 + c0);
        float y0 = fmaxf((pv.x - qv.x) * sc.x + sh.x, 0.f);
        float y1v = fmaxf((pv.y - qv.y) * sc.y + sh.y, 0.f);
        float y2v = fmaxf((pv.z - qv.z) * sc.z + sh.z, 0.f);
        float y3 = fmaxf((pv.w - qv.w) * sc.w + sh.w, 0.f);
        uint2 pk; pk.x = (unsigned)f2bf(y0) | ((unsigned)f2bf(y1v) << 16);
        pk.y = (unsigned)f2bf(y2v) | ((unsigned)f2bf(y3) << 16);
        *(uint2*)(h0b + swz(r, 8 * (idx & 15))) = pk;
    }
    __syncthreads();

    const int l = tid & 63, w = tid >> 6;
    const int mrow = 16 * w + (l & 15);
    const int klane = (l >> 4) * 4;
    {
        short8v a0 = load_frag(h0b, mrow, klane);
        short8v a1 = load_frag(h0b, mrow, klane + 32);
#pragma unroll
        for (int nt = 0; nt < 4; ++nt) {
            float bias = b1[16 * nt + (l & 15)];
            f32x4 acc; acc[0] = bias; acc[1] = bias; acc[2] = bias; acc[3] = bias;
            short8v bA = load_frag(w1b, 16 * nt + (l & 15), klane);
            short8v bB = load_frag(w1b, 16 * nt + (l & 15), klane + 32);
            acc = __builtin_amdgcn_mfma_f32_16x16x32_bf16(a0, bA, acc, 0, 0, 0);
            acc = __builtin_amdgcn_mfma_f32_16x16x32_bf16(a1, bB, acc, 0, 0, 0);
#pragma unroll
            for (int p = 0; p < 4; ++p) {
                int row = 16 * w + (l >> 4) * 4 + p;
                int col = 16 * nt + (l & 15);
                float v = fmaxf(acc[p] * ss[256 + col] + ss[384 + col], 0.f);
                *(unsigned short*)(h1b + swz(row, 2 * col)) = f2bf(v);
            }
        }
    }
    __syncthreads();
    {
        short8v a0 = load_frag(h1b, mrow, klane);
        short8v a1 = load_frag(h1b, mrow, klane + 32);
#pragma unroll
        for (int nt = 0; nt < 8; ++nt) {
            float bias = b2[16 * nt + (l & 15)];
            f32x4 acc; acc[0] = bias; acc[1] = bias; acc[2] = bias; acc[3] = bias;
            short8v bA = load_frag(w2b, 16 * nt + (l & 15), klane);
            short8v bB = load_frag(w2b, 16 * nt + (l & 15), klane + 32);
            acc = __builtin_amdgcn_mfma_f32_16x16x32_bf16(a0, bA, acc, 0, 0, 0);
            acc = __builtin_amdgcn_mfma_f32_16x16x32_bf16(a1, bB, acc, 0, 0, 0);
            float s = acc[0] + acc[1] + acc[2] + acc[3];
            float q = acc[0] * acc[0] + acc[1] * acc[1] + acc[2] * acc[2] + acc[3] * acc[3];
            float m = fmaxf(fmaxf(acc[0], acc[1]), fmaxf(acc[2], acc[3]));
            s += __shfl_xor(s, 16); s += __shfl_xor(s, 32);
            q += __shfl_xor(q, 16); q += __shfl_xor(q, 32);
            m = fmaxf(m, __shfl_xor(m, 16)); m = fmaxf(m, __shfl_xor(m, 32));
            if (l < 16) {
                sredS[w][nt * 16 + l] = s;
                sredQ[w][nt * 16 + l] = q;
                sredM[w][nt * 16 + l] = m;
            }
        }
    }
    __syncthreads();
    if (tid < 128) {
        float s = sredS[0][tid] + sredS[1][tid] + sredS[2][tid] + sredS[3][tid];
        float q = sredQ[0][tid] + sredQ[1][tid] + sredQ[2][tid] + sredQ[3][tid];
        partial[(size_t)blk * 256 + tid]       = s;
        partial[(size_t)blk * 256 + 128 + tid] = q;
        const int bs0 = blk * 2;
        maxy[(size_t)bs0 * 128 + tid]       = fmaxf(sredM[0][tid], sredM[1][tid]);
        maxy[(size_t)(bs0 + 1) * 128 + tid] = fmaxf(sredM[2][tid], sredM[3][tid]);
    }
}

// ---------------- reduce stats -> scale/shift ----------------
__global__ __launch_bounds__(256) void reduce_stats_kernel(
    const float* __restrict__ partial, int Cd, float inv_count,
    const float* __restrict__ g, const float* __restrict__ be,
    float* __restrict__ ss_layer) {
    const int c   = blockIdx.x;
    const int tid = threadIdx.x;
    float s = 0.f, q = 0.f;
    for (int blk = tid; blk < NBLK; blk += 256) {
        s += partial[(size_t)blk * 2 * Cd + c];
        q += partial[(size_t)blk * 2 * Cd + Cd + c];
    }
#pragma unroll
    for (int m = 1; m < 64; m <<= 1) { s += __shfl_xor(s, m); q += __shfl_xor(q, m); }
    __shared__ float ls[4], lq[4];
    const int wid = tid >> 6;
    if ((tid & 63) == 0) { ls[wid] = s; lq[wid] = q; }
    __syncthreads();
    if (tid == 0) {
        s = ls[0] + ls[1] + ls[2] + ls[3];
        q = lq[0] + lq[1] + lq[2] + lq[3];
        float mean = s * inv_count;
        float var  = q * inv_count - mean * mean;
        float sc   = g[c] / sqrtf(var + 1e-5f);
        ss_layer[c]       = sc;
        ss_layer[128 + c] = be[c] - mean * sc;
    }
}

// ---------------- final: BN2 + ReLU applied to max-pooled y2 ----------------
__global__ __launch_bounds__(256) void final_kernel(const float* __restrict__ maxy,
                                                    const float* __restrict__ ss2,
                                                    float* __restrict__ outp) {
    int idx = blockIdx.x * 256 + threadIdx.x;
    int c = idx & 127;
    float v = maxy[idx] * ss2[c] + ss2[128 + c];
    outp[idx] = fmaxf(v, 0.f);
}

extern "C" void kernel_launch(void* const* d_in, const int* in_sizes, int n_in,
                              void* d_out, int out_size, void* d_ws, size_t ws_size,
                              hipStream_t stream) {
    const float* xyz    = (const float*)d_in[0];
    const float* points = (const float*)d_in[1];
    const float* w0 = (const float*)d_in[2];  const float* b0  = (const float*)d_in[3];
    const float* g0 = (const float*)d_in[4];  const float* be0 = (const float*)d_in[5];
    const float* w1 = (const float*)d_in[6];  const float* b1  = (const float*)d_in[7];
    const float* g1 = (const float*)d_in[8];  const float* be1 = (const float*)d_in[9];
    const float* w2 = (const float*)d_in[10]; const float* b2  = (const float*)d_in[11];
    const float* g2 = (const float*)d_in[12]; const float* be2 = (const float*)d_in[13];

    float* out      = (float*)d_out;
    float* new_xyz  = out;                                 // [B, S, 3]
    float* out_pts  = out + (size_t)BATCH * NPOINT * 3;    // [B, S, 128]

    char* p = (char*)d_ws;
    int* gi = (int*)p;          p += (((size_t)ROWS * 4) + 255) & ~(size_t)255;
    float* partial = (float*)p; p += (((size_t)NBLK * 256 * 4) + 255) & ~(size_t)255;
    float* ss = (float*)p;      p += ((size_t)(3 * 256 * 4) + 255) & ~(size_t)255;
    float* maxy = (float*)p;    p += (((size_t)BATCH * NPOINT * 128 * 4) + 255) & ~(size_t)255;
    float* P = (float*)p;       p += (((size_t)BATCH * NPTS * 64 * 4) + 255) & ~(size_t)255;
    float* Q = (float*)p;       // [B*NPOINT][64]

    const float inv_count = 1.0f / (float)ROWS;

    pre_kernel<<<16 + 512, 512, 0, stream>>>(xyz, points, w0, b0, P, new_xyz);
    ballq_kernel<<<(BATCH * NPOINT) / 4, 256, 0, stream>>>(xyz, new_xyz, w0, gi, Q);

    stats0_kernel<<<NBLK, 256, 0, stream>>>(P, Q, gi, partial);
    reduce_stats_kernel<<<64, 256, 0, stream>>>(partial, 64, inv_count, g0, be0, ss + 0);

    chainM1_kernel<<<NBLK, 256, 0, stream>>>(P, Q, gi, w1, b1, ss, partial);
    reduce_stats_kernel<<<64, 256, 0, stream>>>(partial, 64, inv_count, g1, be1, ss + 256);

    chainM2_kernel<<<NBLK, 256, 0, stream>>>(P, Q, gi, w1, b1, w2, b2, ss, partial, maxy);
    reduce_stats_kernel<<<128, 256, 0, stream>>>(partial, 128, inv_count, g2, be2, ss + 512);

    final_kernel<<<(BATCH * NPOINT * 128) / 256, 256, 0, stream>>>(maxy, ss + 512, out_pts);
}